// Round 1
// baseline (2426.573 us; speedup 1.0000x reference)
//
#include <hip/hip_runtime.h>
#include <hip/hip_bf16.h>

#define N_NODES 50000
#define N_EDGES 800000
#define F 64
#define N_GRAPHS 500

// ---------------- scatter: agg[dst] += x[src] ----------------
// one thread per (edge, quad of 4 floats): 16 threads cover one 64-f32 row
__global__ __launch_bounds__(256) void scatter_kernel(
    const float* __restrict__ xin,
    const int* __restrict__ edge,   // [2, N_EDGES] int32
    float* __restrict__ agg)
{
    int gid = blockIdx.x * 256 + threadIdx.x;
    if (gid >= N_EDGES * 16) return;
    int e = gid >> 4;
    int q = (gid & 15) << 2;          // feature offset 0..60 step 4
    int src = edge[e];
    int dst = edge[N_EDGES + e];
    const float4 v = *reinterpret_cast<const float4*>(xin + src * F + q);
    float* p = agg + dst * F + q;
    atomicAdd(p + 0, v.x);
    atomicAdd(p + 1, v.y);
    atomicAdd(p + 2, v.z);
    atomicAdd(p + 3, v.w);
}

// ---------------- fused linear: out = [relu](agg@Wrel^T + brel + x@Wroot^T) ----------------
// wave-per-node; weights transposed in LDS (pad 65 -> conflict-free)
__global__ __launch_bounds__(256) void lin_kernel(
    const float* __restrict__ agg,
    const float* __restrict__ xin,
    const float* __restrict__ Wrel,   // [64][64] row-major (out, in)
    const float* __restrict__ brel,   // [64]
    const float* __restrict__ Wroot,  // [64][64]
    float* __restrict__ out,
    int do_relu)
{
    __shared__ float WrelT[F][F + 1];
    __shared__ float WrootT[F][F + 1];
    __shared__ float rowA[4][F];
    __shared__ float rowX[4][F];

    int tid = threadIdx.x;
    for (int i = tid; i < F * F; i += 256) {
        int o = i >> 6, k = i & 63;
        WrelT[k][o]  = Wrel[i];
        WrootT[k][o] = Wroot[i];
    }
    __syncthreads();

    int wave = tid >> 6, lane = tid & 63;
    int gw = blockIdx.x * 4 + wave;
    int nw = gridDim.x * 4;
    float b = brel[lane];

    for (int n = gw; n < N_NODES; n += nw) {
        rowA[wave][lane] = agg[n * F + lane];
        rowX[wave][lane] = xin[n * F + lane];
        // wave-private LDS: no cross-wave sharing, in-order within wave
        float acc = b;
#pragma unroll
        for (int k = 0; k < F; ++k) {
            acc += rowA[wave][k] * WrelT[k][lane];
            acc += rowX[wave][k] * WrootT[k][lane];
        }
        if (do_relu) acc = fmaxf(acc, 0.0f);
        out[n * F + lane] = acc;
    }
}

// ---------------- pooling: sums[batch[n]] += h[n]; cnt[batch[n]] += 1 ----------------
__global__ __launch_bounds__(256) void pool_kernel(
    const float* __restrict__ h,
    const int* __restrict__ batch,
    float* __restrict__ sums,   // [N_GRAPHS][F]
    float* __restrict__ cnt)    // [N_GRAPHS]
{
    int gid = blockIdx.x * 256 + threadIdx.x;
    if (gid >= N_NODES * 16) return;
    int n = gid >> 4;
    int q = (gid & 15) << 2;
    int g = batch[n];
    const float4 v = *reinterpret_cast<const float4*>(h + n * F + q);
    float* p = sums + g * F + q;
    atomicAdd(p + 0, v.x);
    atomicAdd(p + 1, v.y);
    atomicAdd(p + 2, v.z);
    atomicAdd(p + 3, v.w);
    if ((gid & 15) == 0) atomicAdd(&cnt[g], 1.0f);
}

// ---------------- head: out[g][o] = (sums[g]/max(cnt,1)) . Wlin[o] + blin[o] ----------------
__global__ __launch_bounds__(256) void head_kernel(
    const float* __restrict__ sums,
    const float* __restrict__ cnt,
    const float* __restrict__ Wlin,  // [2][64]
    const float* __restrict__ blin,  // [2]
    float* __restrict__ out)         // [N_GRAPHS][2]
{
    int gid = blockIdx.x * 256 + threadIdx.x;
    if (gid >= N_GRAPHS * 2) return;
    int g = gid >> 1, o = gid & 1;
    float c = fmaxf(cnt[g], 1.0f);
    float acc = 0.0f;
#pragma unroll
    for (int k = 0; k < F; ++k) acc += sums[g * F + k] * Wlin[o * F + k];
    out[gid] = acc / c + blin[o];
}

extern "C" void kernel_launch(void* const* d_in, const int* in_sizes, int n_in,
                              void* d_out, int out_size, void* d_ws, size_t ws_size,
                              hipStream_t stream) {
    const float* x     = (const float*)d_in[0];
    const int*   edge  = (const int*)d_in[1];
    const int*   batch = (const int*)d_in[2];
    const float* Wrel1 = (const float*)d_in[3];
    const float* brel1 = (const float*)d_in[4];
    const float* Wroot1= (const float*)d_in[5];
    const float* Wrel2 = (const float*)d_in[6];
    const float* brel2 = (const float*)d_in[7];
    const float* Wroot2= (const float*)d_in[8];
    const float* Wrel3 = (const float*)d_in[9];
    const float* brel3 = (const float*)d_in[10];
    const float* Wroot3= (const float*)d_in[11];
    const float* Wlin  = (const float*)d_in[12];
    const float* blin  = (const float*)d_in[13];
    float* out = (float*)d_out;

    const size_t nodeBytes = (size_t)N_NODES * F * sizeof(float);  // 12.8 MB
    char* ws = (char*)d_ws;
    float* agg  = (float*)(ws);
    float* hA   = (float*)(ws + nodeBytes);
    float* hB   = (float*)(ws + 2 * nodeBytes);
    float* sums = (float*)(ws + 3 * nodeBytes);
    float* cnt  = (float*)(ws + 3 * nodeBytes + (size_t)N_GRAPHS * F * sizeof(float));

    const int scatterBlocks = (N_EDGES * 16) / 256;       // 50000
    const int linBlocks     = (N_NODES + 3) / 4;          // 12500 (wave-per-node)
    const int poolBlocks    = (N_NODES * 16) / 256;       // 3125
    dim3 blk(256);

    // ---- layer 1: agg = scatter(x); hA = relu(lin(agg, x)) ----
    hipMemsetAsync(agg, 0, nodeBytes, stream);
    scatter_kernel<<<scatterBlocks, blk, 0, stream>>>(x, edge, agg);
    lin_kernel<<<linBlocks, blk, 0, stream>>>(agg, x, Wrel1, brel1, Wroot1, hA, 1);

    // ---- layer 2: agg = scatter(hA); hB = relu(lin(agg, hA)) ----
    hipMemsetAsync(agg, 0, nodeBytes, stream);
    scatter_kernel<<<scatterBlocks, blk, 0, stream>>>(hA, edge, agg);
    lin_kernel<<<linBlocks, blk, 0, stream>>>(agg, hA, Wrel2, brel2, Wroot2, hB, 1);

    // ---- layer 3: agg = scatter(hB); hA = lin(agg, hB) (no relu) ----
    hipMemsetAsync(agg, 0, nodeBytes, stream);
    scatter_kernel<<<scatterBlocks, blk, 0, stream>>>(hB, edge, agg);
    lin_kernel<<<linBlocks, blk, 0, stream>>>(agg, hB, Wrel3, brel3, Wroot3, hA, 0);

    // ---- pool + head ----
    hipMemsetAsync(sums, 0, (size_t)N_GRAPHS * F * sizeof(float) + (size_t)N_GRAPHS * sizeof(float), stream);
    pool_kernel<<<poolBlocks, blk, 0, stream>>>(hA, batch, sums, cnt);
    head_kernel<<<(N_GRAPHS * 2 + 255) / 256, blk, 0, stream>>>(sums, cnt, Wlin, blin, out);
}

// Round 2
// 638.510 us; speedup vs baseline: 3.8004x; 3.8004x over previous
//
#include <hip/hip_runtime.h>
#include <hip/hip_bf16.h>

#define N_NODES 50000
#define N_EDGES 800000
#define F 64
#define N_GRAPHS 500

// ---------------- CSR build step 1: deg[dst]++ ----------------
__global__ __launch_bounds__(256) void hist_kernel(
    const int* __restrict__ edge, int* __restrict__ deg)
{
    int e = blockIdx.x * 256 + threadIdx.x;
    if (e < N_EDGES) atomicAdd(&deg[edge[N_EDGES + e]], 1);
}

// ---------------- CSR build step 2: exclusive scan (single block) ----------------
__global__ __launch_bounds__(1024) void scan_kernel(
    const int* __restrict__ deg, int* __restrict__ off, int* __restrict__ cursor)
{
    __shared__ int wsum[16];
    __shared__ int carry_s;
    int tid = threadIdx.x;
    int lane = tid & 63, wave = tid >> 6;
    if (tid == 0) carry_s = 0;
    __syncthreads();
    for (int base = 0; base < N_NODES; base += 1024) {
        int i = base + tid;
        int v = (i < N_NODES) ? deg[i] : 0;
        int incl = v;
#pragma unroll
        for (int d = 1; d < 64; d <<= 1) {
            int t = __shfl_up(incl, d);
            if (lane >= d) incl += t;
        }
        if (lane == 63) wsum[wave] = incl;
        __syncthreads();
        if (wave == 0 && lane < 16) {
            int ws = wsum[lane];
#pragma unroll
            for (int d = 1; d < 16; d <<= 1) {
                int t = __shfl_up(ws, d);
                if (lane >= d) ws += t;
            }
            wsum[lane] = ws;
        }
        __syncthreads();
        int total = wsum[15];
        int wbase = (wave == 0) ? 0 : wsum[wave - 1];
        int excl = carry_s + wbase + incl - v;
        if (i < N_NODES) { off[i] = excl; cursor[i] = excl; }
        __syncthreads();
        if (tid == 0) carry_s += total;
        // barrier at top of next iteration (or below) orders carry_s update
    }
    __syncthreads();
    if (tid == 0) off[N_NODES] = carry_s;
}

// ---------------- CSR build step 3: fill src lists ----------------
__global__ __launch_bounds__(256) void fill_kernel(
    const int* __restrict__ edge, int* __restrict__ cursor, int* __restrict__ csr_src)
{
    int e = blockIdx.x * 256 + threadIdx.x;
    if (e < N_EDGES) {
        int dst = edge[N_EDGES + e];
        int slot = atomicAdd(&cursor[dst], 1);
        csr_src[slot] = edge[e];
    }
}

// ---------------- fused layer: gather + (agg@Wrel^T + brel + x@Wroot^T) [+relu] ----------------
// wave-per-node grid-stride; weights transposed in LDS (pad 65 -> conflict-free)
__global__ __launch_bounds__(256) void layer_kernel(
    const float* __restrict__ xin,
    const int* __restrict__ off,
    const int* __restrict__ csr_src,
    const float* __restrict__ Wrel,   // [64][64] (out, in)
    const float* __restrict__ brel,
    const float* __restrict__ Wroot,
    float* __restrict__ out,
    int do_relu)
{
    __shared__ float WrelT[F][F + 1];
    __shared__ float WrootT[F][F + 1];
    __shared__ float rowA[4][F];
    __shared__ float rowX[4][F];

    int tid = threadIdx.x;
    for (int i = tid; i < F * F; i += 256) {
        int o = i >> 6, k = i & 63;
        WrelT[k][o]  = Wrel[i];
        WrootT[k][o] = Wroot[i];
    }
    __syncthreads();

    int wave = tid >> 6, lane = tid & 63;
    float b = brel[lane];
    int gw = blockIdx.x * 4 + wave;
    int nw = gridDim.x * 4;

    for (int n = gw; n < N_NODES; n += nw) {
        int beg = off[n], end = off[n + 1];
        // gather: sum x[src] rows, 4-deep unrolled for memory-level parallelism
        float a0 = 0.f, a1 = 0.f, a2 = 0.f, a3 = 0.f;
        int j = beg;
        for (; j + 4 <= end; j += 4) {
            int s0 = csr_src[j], s1 = csr_src[j + 1], s2 = csr_src[j + 2], s3 = csr_src[j + 3];
            a0 += xin[s0 * F + lane];
            a1 += xin[s1 * F + lane];
            a2 += xin[s2 * F + lane];
            a3 += xin[s3 * F + lane];
        }
        for (; j < end; ++j) a0 += xin[csr_src[j] * F + lane];
        rowA[wave][lane] = (a0 + a1) + (a2 + a3);
        rowX[wave][lane] = xin[n * F + lane];
        // wave-private LDS rows: in-wave write->read, compiler inserts lgkmcnt waits
        float acc = b;
#pragma unroll
        for (int k = 0; k < F; ++k) {
            acc += rowA[wave][k] * WrelT[k][lane];
            acc += rowX[wave][k] * WrootT[k][lane];
        }
        if (do_relu) acc = fmaxf(acc, 0.0f);
        out[n * F + lane] = acc;
    }
}

// ---------------- fused pool (mean over contiguous node range) + head ----------------
__global__ __launch_bounds__(256) void pool_head_kernel(
    const float* __restrict__ h,
    const int* __restrict__ batch,   // sorted
    const float* __restrict__ Wlin,  // [2][64]
    const float* __restrict__ blin,  // [2]
    float* __restrict__ out)         // [N_GRAPHS][2]
{
    __shared__ float psum[4][F];
    __shared__ float pooled[F];
    int g = blockIdx.x;
    int tid = threadIdx.x, wave = tid >> 6, lane = tid & 63;

    // lower_bound(g) and lower_bound(g+1) over sorted batch (all threads, L2 hits)
    int lo = 0, hi = N_NODES;
    while (lo < hi) { int mid = (lo + hi) >> 1; if (batch[mid] < g) lo = mid + 1; else hi = mid; }
    int s = lo;
    hi = N_NODES;
    while (lo < hi) { int mid = (lo + hi) >> 1; if (batch[mid] < g + 1) lo = mid + 1; else hi = mid; }
    int e = lo;

    float acc = 0.f;
    for (int n = s + wave; n < e; n += 4) acc += h[n * F + lane];
    psum[wave][lane] = acc;
    __syncthreads();
    if (wave == 0) {
        float p = psum[0][lane] + psum[1][lane] + psum[2][lane] + psum[3][lane];
        float c = (float)(e - s);
        pooled[lane] = p / fmaxf(c, 1.0f);
    }
    __syncthreads();
    if (tid < 2) {
        float acc2 = 0.f;
#pragma unroll
        for (int k = 0; k < F; ++k) acc2 += pooled[k] * Wlin[tid * F + k];
        out[g * 2 + tid] = acc2 + blin[tid];
    }
}

extern "C" void kernel_launch(void* const* d_in, const int* in_sizes, int n_in,
                              void* d_out, int out_size, void* d_ws, size_t ws_size,
                              hipStream_t stream) {
    const float* x     = (const float*)d_in[0];
    const int*   edge  = (const int*)d_in[1];
    const int*   batch = (const int*)d_in[2];
    const float* Wrel1 = (const float*)d_in[3];
    const float* brel1 = (const float*)d_in[4];
    const float* Wroot1= (const float*)d_in[5];
    const float* Wrel2 = (const float*)d_in[6];
    const float* brel2 = (const float*)d_in[7];
    const float* Wroot2= (const float*)d_in[8];
    const float* Wrel3 = (const float*)d_in[9];
    const float* brel3 = (const float*)d_in[10];
    const float* Wroot3= (const float*)d_in[11];
    const float* Wlin  = (const float*)d_in[12];
    const float* blin  = (const float*)d_in[13];
    float* out = (float*)d_out;

    char* ws = (char*)d_ws;
    size_t p = 0;
    int* deg     = (int*)(ws + p); p += (size_t)N_NODES * 4;
    int* off     = (int*)(ws + p); p += (size_t)(N_NODES + 1) * 4;
    int* cursor  = (int*)(ws + p); p += (size_t)N_NODES * 4;
    p = (p + 255) & ~(size_t)255;
    int* csr_src = (int*)(ws + p); p += (size_t)N_EDGES * 4;
    p = (p + 255) & ~(size_t)255;
    float* hA    = (float*)(ws + p); p += (size_t)N_NODES * F * 4;
    float* hB    = (float*)(ws + p); p += (size_t)N_NODES * F * 4;

    dim3 blk(256);
    const int edgeBlocks = (N_EDGES + 255) / 256;  // 3125

    // ---- CSR build (once per call, reused by all 3 layers) ----
    hipMemsetAsync(deg, 0, (size_t)N_NODES * 4, stream);
    hist_kernel<<<edgeBlocks, blk, 0, stream>>>(edge, deg);
    scan_kernel<<<1, 1024, 0, stream>>>(deg, off, cursor);
    fill_kernel<<<edgeBlocks, blk, 0, stream>>>(edge, cursor, csr_src);

    // ---- 3 fused GraphConv layers (gather + dual linear + relu) ----
    layer_kernel<<<1024, blk, 0, stream>>>(x,  off, csr_src, Wrel1, brel1, Wroot1, hA, 1);
    layer_kernel<<<1024, blk, 0, stream>>>(hA, off, csr_src, Wrel2, brel2, Wroot2, hB, 1);
    layer_kernel<<<1024, blk, 0, stream>>>(hB, off, csr_src, Wrel3, brel3, Wroot3, hA, 0);

    // ---- fused mean-pool + head ----
    pool_head_kernel<<<N_GRAPHS, blk, 0, stream>>>(hA, batch, Wlin, blin, out);
}

// Round 4
// 534.253 us; speedup vs baseline: 4.5420x; 1.1951x over previous
//
#include <hip/hip_runtime.h>
#include <hip/hip_bf16.h>

#define N_NODES 50000
#define N_EDGES 800000
#define F 64
#define N_GRAPHS 500
#define NW ((N_NODES + 63) / 64)   // 782 wave-segments of the node array

// ---------------- CSR build step 1: deg[dst]++ ----------------
__global__ __launch_bounds__(256) void hist_kernel(
    const int* __restrict__ edge, int* __restrict__ deg)
{
    int e = blockIdx.x * 256 + threadIdx.x;
    if (e < N_EDGES) atomicAdd(&deg[edge[N_EDGES + e]], 1);
}

// ---------------- CSR build step 2a: per-64-chunk sums ----------------
__global__ __launch_bounds__(256) void wavesum_kernel(
    const int* __restrict__ deg, int* __restrict__ partial)
{
    int w = (blockIdx.x * 256 + threadIdx.x) >> 6;
    int lane = threadIdx.x & 63;
    if (w >= NW) return;
    int i = w * 64 + lane;
    int v = (i < N_NODES) ? deg[i] : 0;
#pragma unroll
    for (int d = 32; d > 0; d >>= 1) v += __shfl_xor(v, d);
    if (lane == 0) partial[w] = v;
}

// ---------------- CSR build step 2b: single-block exclusive scan of partial[NW] ----------------
__global__ __launch_bounds__(1024) void scanp_kernel(int* __restrict__ partial)
{
    __shared__ int ws[16];
    int t = threadIdx.x, lane = t & 63, wv = t >> 6;
    int v = (t < NW) ? partial[t] : 0;
    int incl = v;
#pragma unroll
    for (int d = 1; d < 64; d <<= 1) { int u = __shfl_up(incl, d); if (lane >= d) incl += u; }
    if (lane == 63) ws[wv] = incl;
    __syncthreads();
    if (wv == 0 && lane < 16) {
        int s = ws[lane];
#pragma unroll
        for (int d = 1; d < 16; d <<= 1) { int u = __shfl_up(s, d); if (lane >= d) s += u; }
        ws[lane] = s;
    }
    __syncthreads();
    int base = wv ? ws[wv - 1] : 0;
    if (t < NW) partial[t] = base + incl - v;     // exclusive scan in place
    if (t == 0) partial[NW] = ws[15];             // grand total
}

// ---------------- CSR build step 2c: per-chunk offsets ----------------
__global__ __launch_bounds__(256) void offsets_kernel(
    const int* __restrict__ deg, const int* __restrict__ partial,
    int* __restrict__ off, int* __restrict__ cursor)
{
    int w = (blockIdx.x * 256 + threadIdx.x) >> 6;
    int lane = threadIdx.x & 63;
    if (w >= NW) return;
    int i = w * 64 + lane;
    int v = (i < N_NODES) ? deg[i] : 0;
    int incl = v;
#pragma unroll
    for (int d = 1; d < 64; d <<= 1) { int u = __shfl_up(incl, d); if (lane >= d) incl += u; }
    int excl = partial[w] + incl - v;
    if (i < N_NODES) { off[i] = excl; cursor[i] = excl; }
    if (w == 0 && lane == 0) off[N_NODES] = partial[NW];
}

// ---------------- CSR build step 3: fill src lists ----------------
__global__ __launch_bounds__(256) void fill_kernel(
    const int* __restrict__ edge, int* __restrict__ cursor, int* __restrict__ csr_src)
{
    int e = blockIdx.x * 256 + threadIdx.x;
    if (e < N_EDGES) {
        int dst = edge[N_EDGES + e];
        int slot = atomicAdd(&cursor[dst], 1);
        csr_src[slot] = edge[e];
    }
}

// ---------------- gather: agg[n] = sum_{src in csr[n]} x[src]  (wave-per-node) ----------------
// csr indices are wave-uniform -> s_load; row loads coalesced 256B; no LDS, low VGPR.
__global__ __launch_bounds__(256) void gather_kernel(
    const float* __restrict__ xin, const int* __restrict__ off,
    const int* __restrict__ csr_src, float* __restrict__ agg)
{
    int w = (blockIdx.x * 256 + threadIdx.x) >> 6;
    int lane = threadIdx.x & 63;
    if (w >= N_NODES) return;
    int beg = off[w], end = off[w + 1];
    float a0 = 0.f, a1 = 0.f, a2 = 0.f, a3 = 0.f;
    int j = beg;
    for (; j + 4 <= end; j += 4) {
        int s0 = csr_src[j], s1 = csr_src[j + 1], s2 = csr_src[j + 2], s3 = csr_src[j + 3];
        a0 += xin[s0 * F + lane];
        a1 += xin[s1 * F + lane];
        a2 += xin[s2 * F + lane];
        a3 += xin[s3 * F + lane];
    }
    for (; j < end; ++j) a0 += xin[csr_src[j] * F + lane];
    agg[w * F + lane] = (a0 + a1) + (a2 + a3);
}

// ---------------- transposed linear: lane = node, wave owns 16 outputs ----------------
// out[n][ob+j] = relu( sum_k agg[n][k]*Wrel[ob+j][k] + x[n][k]*Wroot[ob+j][k] + brel[ob+j] )
// W addresses are wave-uniform -> SGPR loads; pure v_fmac vgpr,sgpr,vgpr; zero LDS.
__global__ __launch_bounds__(256) void linear_kernel(
    const float* __restrict__ agg, const float* __restrict__ xin,
    const float* __restrict__ Wrel, const float* __restrict__ brel,
    const float* __restrict__ Wroot, float* __restrict__ out, int do_relu)
{
    int lane = threadIdx.x & 63;
    int ob = (threadIdx.x >> 6) * 16;          // wave's output slice
    int n = blockIdx.x * 64 + lane;
    bool valid = n < N_NODES;
    int nn = valid ? n : (N_NODES - 1);        // clamp: keep loads in-bounds

    float acc[16];
#pragma unroll
    for (int j = 0; j < 16; ++j) acc[j] = brel[ob + j];

#pragma unroll
    for (int half = 0; half < 2; ++half) {
        const float* __restrict__ A = half ? xin : agg;
        const float* __restrict__ W = half ? Wroot : Wrel;
        const float* Arow = A + (size_t)nn * F;
        for (int kc = 0; kc < F; kc += 8) {
            float4 a0 = *reinterpret_cast<const float4*>(Arow + kc);
            float4 a1 = *reinterpret_cast<const float4*>(Arow + kc + 4);
#pragma unroll
            for (int j = 0; j < 16; ++j) {
                const float* wr = W + (ob + j) * F + kc;   // wave-uniform -> s_load
                acc[j] += a0.x * wr[0] + a0.y * wr[1] + a0.z * wr[2] + a0.w * wr[3]
                        + a1.x * wr[4] + a1.y * wr[5] + a1.z * wr[6] + a1.w * wr[7];
            }
        }
    }
    if (do_relu) {
#pragma unroll
        for (int j = 0; j < 16; ++j) acc[j] = fmaxf(acc[j], 0.f);
    }
    if (valid) {
#pragma unroll
        for (int j = 0; j < 16; j += 4)
            *reinterpret_cast<float4*>(out + (size_t)n * F + ob + j) =
                make_float4(acc[j], acc[j + 1], acc[j + 2], acc[j + 3]);
    }
}

// ---------------- fused pool (mean over contiguous node range) + head ----------------
__global__ __launch_bounds__(256) void pool_head_kernel(
    const float* __restrict__ h,
    const int* __restrict__ batch,   // sorted
    const float* __restrict__ Wlin,  // [2][64]
    const float* __restrict__ blin,  // [2]
    float* __restrict__ out)         // [N_GRAPHS][2]
{
    __shared__ float psum[4][F];
    __shared__ float pooled[F];
    int g = blockIdx.x;
    int tid = threadIdx.x, wave = tid >> 6, lane = tid & 63;

    int lo = 0, hi = N_NODES;
    while (lo < hi) { int mid = (lo + hi) >> 1; if (batch[mid] < g) lo = mid + 1; else hi = mid; }
    int s = lo;
    hi = N_NODES;
    while (lo < hi) { int mid = (lo + hi) >> 1; if (batch[mid] < g + 1) lo = mid + 1; else hi = mid; }
    int e = lo;

    float acc = 0.f;
    for (int n = s + wave; n < e; n += 4) acc += h[n * F + lane];
    psum[wave][lane] = acc;
    __syncthreads();
    if (wave == 0) {
        float p = psum[0][lane] + psum[1][lane] + psum[2][lane] + psum[3][lane];
        float c = (float)(e - s);
        pooled[lane] = p / fmaxf(c, 1.0f);
    }
    __syncthreads();
    if (tid < 2) {
        float acc2 = 0.f;
#pragma unroll
        for (int k = 0; k < F; ++k) acc2 += pooled[k] * Wlin[tid * F + k];
        out[g * 2 + tid] = acc2 + blin[tid];
    }
}

extern "C" void kernel_launch(void* const* d_in, const int* in_sizes, int n_in,
                              void* d_out, int out_size, void* d_ws, size_t ws_size,
                              hipStream_t stream) {
    const float* x     = (const float*)d_in[0];
    const int*   edge  = (const int*)d_in[1];
    const int*   batch = (const int*)d_in[2];
    const float* Wrel1 = (const float*)d_in[3];
    const float* brel1 = (const float*)d_in[4];
    const float* Wroot1= (const float*)d_in[5];
    const float* Wrel2 = (const float*)d_in[6];
    const float* brel2 = (const float*)d_in[7];
    const float* Wroot2= (const float*)d_in[8];
    const float* Wrel3 = (const float*)d_in[9];
    const float* brel3 = (const float*)d_in[10];
    const float* Wroot3= (const float*)d_in[11];
    const float* Wlin  = (const float*)d_in[12];
    const float* blin  = (const float*)d_in[13];
    float* out = (float*)d_out;

    char* ws = (char*)d_ws;
    size_t p = 0;
    int* deg     = (int*)(ws + p); p += (size_t)N_NODES * 4;
    int* off     = (int*)(ws + p); p += (size_t)(N_NODES + 1) * 4;
    int* cursor  = (int*)(ws + p); p += (size_t)N_NODES * 4;
    int* partial = (int*)(ws + p); p += (size_t)(NW + 1) * 4;
    p = (p + 255) & ~(size_t)255;
    int* csr_src = (int*)(ws + p); p += (size_t)N_EDGES * 4;
    p = (p + 255) & ~(size_t)255;
    float* agg   = (float*)(ws + p); p += (size_t)N_NODES * F * 4;
    float* hA    = (float*)(ws + p); p += (size_t)N_NODES * F * 4;
    float* hB    = (float*)(ws + p); p += (size_t)N_NODES * F * 4;

    dim3 blk(256);
    const int edgeBlocks = (N_EDGES + 255) / 256;   // 3125
    const int nodeWaveBlocks = (N_NODES + 3) / 4;   // 12500 (wave-per-node)
    const int segBlocks = (NW + 3) / 4;             // 196
    const int linBlocks = NW;                       // 782 (64 nodes per block)

    // ---- CSR build ----
    hipMemsetAsync(deg, 0, (size_t)N_NODES * 4, stream);
    hist_kernel<<<edgeBlocks, blk, 0, stream>>>(edge, deg);
    wavesum_kernel<<<segBlocks, blk, 0, stream>>>(deg, partial);
    scanp_kernel<<<1, 1024, 0, stream>>>(partial);
    offsets_kernel<<<segBlocks, blk, 0, stream>>>(deg, partial, off, cursor);
    fill_kernel<<<edgeBlocks, blk, 0, stream>>>(edge, cursor, csr_src);

    // ---- 3 GraphConv layers: gather + transposed dual-linear ----
    gather_kernel<<<nodeWaveBlocks, blk, 0, stream>>>(x, off, csr_src, agg);
    linear_kernel<<<linBlocks, blk, 0, stream>>>(agg, x, Wrel1, brel1, Wroot1, hA, 1);

    gather_kernel<<<nodeWaveBlocks, blk, 0, stream>>>(hA, off, csr_src, agg);
    linear_kernel<<<linBlocks, blk, 0, stream>>>(agg, hA, Wrel2, brel2, Wroot2, hB, 1);

    gather_kernel<<<nodeWaveBlocks, blk, 0, stream>>>(hB, off, csr_src, agg);
    linear_kernel<<<linBlocks, blk, 0, stream>>>(agg, hB, Wrel3, brel3, Wroot3, hA, 0);

    // ---- fused mean-pool + head ----
    pool_head_kernel<<<N_GRAPHS, blk, 0, stream>>>(hA, batch, Wlin, blin, out);
}